// Round 1
// baseline (240.837 us; speedup 1.0000x reference)
//
#include <hip/hip_runtime.h>
#include <hip/hip_bf16.h>
#include <math.h>
#include <stdint.h>

// Problem constants (B,S,H) = (8,128,768)
#define S_LEN 128
#define H_DIM 768
#define B_DIM 8
#define NPAIR 8256          // S*(S+1)/2
#define MROWS 1024          // B*S
#define NTOT  3072          // 4*H : [Ax | Bx(+beta) | Gx | Ay(+cat_b)]
#define EPSC  1e-12f
#define CHUNK 8             // pairs per epilogue block (NPAIR = 1032*8 exactly)

typedef __bf16 bf16x8 __attribute__((ext_vector_type(8)));
typedef float  f32x4  __attribute__((ext_vector_type(4)));

// RNE float -> bf16 (inputs finite)
static __device__ __forceinline__ unsigned short f2bf(float f) {
  union { float f; unsigned u; } a; a.f = f;
  unsigned u = a.u;
  u += 0x7fffu + ((u >> 16) & 1u);
  return (unsigned short)(u >> 16);
}
static __device__ __forceinline__ float bf2f(unsigned short s) {
  union { unsigned u; float f; } a; a.u = ((unsigned)s) << 16;
  return a.f;
}
static __device__ __forceinline__ float4 ld_bf4(const unsigned short* p) {
  ushort4 u = *(const ushort4*)p;
  float4 f; f.x = bf2f(u.x); f.y = bf2f(u.y); f.z = bf2f(u.z); f.w = bf2f(u.w);
  return f;
}

// -------------------- prep --------------------
// blocks [0,1024)            : convert x,y rows -> bf16; row stats of y; Cy = (y-mean)*inv (fp32)
// blocks [1024,1024+2304)    : pack W rows -> Wb[3072][768] bf16
// blocks [3328,3331)         : pack bias3072 = [0 | beta | 0 | cat_b] fp32
__global__ __launch_bounds__(256) void prep(const float* __restrict__ x,
                                            const float* __restrict__ y,
                                            const float* __restrict__ catW,
                                            const float* __restrict__ betaW,
                                            const float* __restrict__ gammaW,
                                            const float* __restrict__ catb,
                                            const float* __restrict__ beta,
                                            unsigned short* __restrict__ Xb,
                                            unsigned short* __restrict__ Yb,
                                            unsigned short* __restrict__ Wb,
                                            float* __restrict__ Cy,
                                            float* __restrict__ bias) {
  __shared__ float ls[4], ls2[4];
  const int bid = blockIdx.x;
  const int tid = threadIdx.x;
  if (bid < MROWS) {
    const int row = bid;
    const int o = tid * 4;
    float s = 0.f, s2 = 0.f;
    float4 vy = make_float4(0.f, 0.f, 0.f, 0.f);
    if (tid < 192) {
      float4 vx = *(const float4*)(x + (size_t)row * H_DIM + o);
      vy = *(const float4*)(y + (size_t)row * H_DIM + o);
      ushort4 ox; ox.x = f2bf(vx.x); ox.y = f2bf(vx.y); ox.z = f2bf(vx.z); ox.w = f2bf(vx.w);
      ushort4 oy; oy.x = f2bf(vy.x); oy.y = f2bf(vy.y); oy.z = f2bf(vy.z); oy.w = f2bf(vy.w);
      *(ushort4*)(Xb + (size_t)row * H_DIM + o) = ox;
      *(ushort4*)(Yb + (size_t)row * H_DIM + o) = oy;
      s  = vy.x + vy.y + vy.z + vy.w;
      s2 = vy.x * vy.x + vy.y * vy.y + vy.z * vy.z + vy.w * vy.w;
    }
    for (int off = 32; off > 0; off >>= 1) { s += __shfl_down(s, off); s2 += __shfl_down(s2, off); }
    if ((tid & 63) == 0) { ls[tid >> 6] = s; ls2[tid >> 6] = s2; }
    __syncthreads();
    const float S1 = ls[0] + ls[1] + ls[2] + ls[3];
    const float S2 = ls2[0] + ls2[1] + ls2[2] + ls2[3];
    const float m  = S1 / H_DIM;
    const float var = S2 / H_DIM - m * m;
    const float st = var + EPSC;                 // reference: std = (var+eps)**2
    const float iv = 1.0f / (st * st);
    if (tid < 192) {
      float4 cy;
      cy.x = (vy.x - m) * iv; cy.y = (vy.y - m) * iv;
      cy.z = (vy.z - m) * iv; cy.w = (vy.w - m) * iv;
      *(float4*)(Cy + (size_t)row * H_DIM + o) = cy;
    }
  } else if (bid < MROWS + 2304) {
    // ---- pack weights: Wb[3072][768] bf16 ----
    int idx = (bid - MROWS) * 256 + tid;     // one float4 per thread
    int e = idx * 4;
    int n = e / H_DIM, k = e % H_DIM;
    const float* src;
    if      (n < 768)  src = catW   + (size_t)n * 1536 + k;
    else if (n < 1536) src = betaW  + (size_t)(n - 768) * 768 + k;
    else if (n < 2304) src = gammaW + (size_t)(n - 1536) * 768 + k;
    else               src = catW   + (size_t)(n - 2304) * 1536 + 768 + k;
    float4 v = *(const float4*)src;
    ushort4 o4; o4.x = f2bf(v.x); o4.y = f2bf(v.y); o4.z = f2bf(v.z); o4.w = f2bf(v.w);
    *(ushort4*)(Wb + e) = o4;
  } else {
    // ---- pack bias3072: [0 | beta | 0(gamma kept separate) | cat_b] ----
    int idx = (bid - MROWS - 2304) * 256 + tid;
    int e = idx * 4;                              // 0..3068, boundaries are x4-aligned
    float4 v = make_float4(0.f, 0.f, 0.f, 0.f);
    if (e >= 768 && e < 1536) v = *(const float4*)(beta + (e - 768));
    else if (e >= 2304)       v = *(const float4*)(catb + (e - 2304));
    *(float4*)(bias + e) = v;
  }
}

// -------------------- MFMA GEMM, 64x64 tiles, BK=64, 2-phase double-buffered --------------------
// LDS layout per tile: [row][8 chunks of 16B], chunk XOR-swizzled: phys chunk c holds logical c^(row&7).
// global_load_lds writes linearly (wave-uniform base + lane*16) -> swizzle applied on the GLOBAL source
// address (m173 / rule 21); ds_read_b128 applies the same XOR. 8-lane groups then cover all 32 banks
// exactly once -> conflict-free (was 8-way).
__device__ __forceinline__ void gload_lds16(const void* g, void* l) {
  __builtin_amdgcn_global_load_lds(
      (const __attribute__((address_space(1))) unsigned int*)(uintptr_t)g,
      (__attribute__((address_space(3))) unsigned int*)(uintptr_t)l,
      16, 0, 0);
}

__global__ __launch_bounds__(256) void gemm_bt(const unsigned short* __restrict__ Xb,
                                               const unsigned short* __restrict__ Yb,
                                               const unsigned short* __restrict__ Wb,
                                               const float* __restrict__ bias,
                                               unsigned short* __restrict__ P) {
  __shared__ unsigned short As[2][64 * 64];   // 16 KiB
  __shared__ unsigned short Bs[2][64 * 64];   // 16 KiB
  const int m0 = blockIdx.x * 64;
  const int n0 = blockIdx.y * 64;
  const unsigned short* A = (n0 < 2304) ? Xb : Yb;   // Ay part multiplies y, not x
  const unsigned short* Arow = A + (size_t)m0 * H_DIM;
  const unsigned short* Brow = Wb + (size_t)n0 * H_DIM;

  const int tid  = threadIdx.x;
  const int lane = tid & 63;
  const int wave = tid >> 6;
  const int wm = (wave >> 1) * 32;
  const int wn = (wave & 1) * 32;
  const int quad = lane >> 4;
  const int r    = lane & 15;

  // staging: 16B chunks; tile = 64 rows x 8 chunks = 512 chunks; thread stages chunks tid and tid+256
  const int q0 = tid, q1 = tid + 256;
  const int sr0 = q0 >> 3, sc0 = (q0 & 7) ^ (sr0 & 7);
  const int sr1 = q1 >> 3, sc1 = (q1 & 7) ^ (sr1 & 7);
  const size_t aoff0 = (size_t)sr0 * H_DIM + sc0 * 8;   // elements
  const size_t aoff1 = (size_t)sr1 * H_DIM + sc1 * 8;

  // ds_read element offsets for the 8 fragments per K-step (swizzled)
  int ard[2][2], brd[2][2];   // [ks][mi]
#pragma unroll
  for (int ks = 0; ks < 2; ++ks)
#pragma unroll
    for (int mi = 0; mi < 2; ++mi) {
      const int rowA = wm + mi * 16 + r;
      const int rowB = wn + mi * 16 + r;
      ard[ks][mi] = rowA * 64 + ((((ks << 2) | quad) ^ (rowA & 7)) << 3);
      brd[ks][mi] = rowB * 64 + ((((ks << 2) | quad) ^ (rowB & 7)) << 3);
    }

  f32x4 acc[2][2] = {};

  auto stage = [&](int buf, int k0) {
    gload_lds16(Arow + aoff0 + k0, &As[buf][q0 * 8]);
    gload_lds16(Arow + aoff1 + k0, &As[buf][q1 * 8]);
    gload_lds16(Brow + aoff0 + k0, &Bs[buf][q0 * 8]);
    gload_lds16(Brow + aoff1 + k0, &Bs[buf][q1 * 8]);
  };
  auto compute = [&](int buf) {
    bf16x8 af[2][2], bfr[2][2];
#pragma unroll
    for (int ks = 0; ks < 2; ++ks)
#pragma unroll
      for (int mi = 0; mi < 2; ++mi) {
        af[ks][mi]  = *(const bf16x8*)&As[buf][ard[ks][mi]];
        bfr[ks][mi] = *(const bf16x8*)&Bs[buf][brd[ks][mi]];
      }
#pragma unroll
    for (int ks = 0; ks < 2; ++ks)        // ks outer keeps K accumulation order identical
#pragma unroll
      for (int mi = 0; mi < 2; ++mi)
#pragma unroll
        for (int ni = 0; ni < 2; ++ni)
          acc[mi][ni] = __builtin_amdgcn_mfma_f32_16x16x32_bf16(af[ks][mi], bfr[ks][ni], acc[mi][ni], 0, 0, 0);
  };

  // 2-phase pipeline: stage(t+1) issued BEFORE compute(t); single barrier per K-step.
  // __syncthreads() drains vmcnt(0) (compiler-inserted), so stage(t+1) is complete at loop top.
  stage(0, 0);
  __syncthreads();
  int cur = 0;
  for (int k0 = 64; k0 < H_DIM; k0 += 64) {
    stage(cur ^ 1, k0);
    compute(cur);
    __syncthreads();
    cur ^= 1;
  }
  compute(cur);

  // store with bias fold (bias=0 for Ax/Gx columns -> bitwise identical P there)
#pragma unroll
  for (int ni = 0; ni < 2; ++ni) {
    const int col = n0 + wn + ni * 16 + r;
    const float bv = bias[col];
#pragma unroll
    for (int mi = 0; mi < 2; ++mi) {
      const int row = m0 + wm + mi * 16 + quad * 4;   // C/D: col=lane&15, row=quad*4+reg
#pragma unroll
      for (int reg = 0; reg < 4; ++reg)
        P[(size_t)(row + reg) * NTOT + col] = f2bf(acc[mi][ni][reg] + bv);
    }
  }
}

// -------------------- epilogue: 8 pairs per block, i-row cached in registers --------------------
// out = 0.5*(relu(ax+ay) + cy*(gx+gamma) + bx)   [cat_b folded into ay, beta into bx, cy=(y-m)*inv]
// nontemporal stores keep the 203 MB output stream from thrashing per-XCD L2 (P and Cy stay hot).
__global__ __launch_bounds__(192) void epilogue(const unsigned short* __restrict__ P,
                                                const float* __restrict__ Cy,
                                                const float* __restrict__ gamma,
                                                float* __restrict__ out) {
  const int b  = blockIdx.y;
  const int p0 = blockIdx.x * CHUNK;
  const int o  = threadIdx.x * 4;

  // off(i) = i*(257-i)/2 ; find i for p0
  int i = (int)((257.0 - sqrt(257.0 * 257.0 - 8.0 * (double)p0)) * 0.5);
  if (i < 0) i = 0;
  if (i > S_LEN - 1) i = S_LEN - 1;
  while ((i + 1) * (256 - i) / 2 <= p0) ++i;
  while (i * (257 - i) / 2 > p0) --i;

  float4 ga = *(const float4*)(gamma + o);

  size_t ri = (size_t)(b * S_LEN + i) * NTOT;
  float4 ax = ld_bf4(P + ri + o);
  float4 bx = ld_bf4(P + ri + 768 + o);
  float4 gx = ld_bf4(P + ri + 1536 + o);

#pragma unroll
  for (int t = 0; t < CHUNK; ++t) {
    const int p = p0 + t;
    bool moved = false;
    while ((i + 1) * (256 - i) / 2 <= p) { ++i; moved = true; }
    if (moved) {
      ri = (size_t)(b * S_LEN + i) * NTOT;
      ax = ld_bf4(P + ri + o);
      bx = ld_bf4(P + ri + 768 + o);
      gx = ld_bf4(P + ri + 1536 + o);
    }
    const int j = i + (p - i * (257 - i) / 2);
    const int rowj = b * S_LEN + j;
    float4 ay = ld_bf4(P + (size_t)rowj * NTOT + 2304 + o);
    float4 cy = *(const float4*)(Cy + (size_t)rowj * H_DIM + o);
    f32x4 rr;
    rr[0] = 0.5f * (fmaxf(ax.x + ay.x, 0.f) + cy.x * (gx.x + ga.x) + bx.x);
    rr[1] = 0.5f * (fmaxf(ax.y + ay.y, 0.f) + cy.y * (gx.y + ga.y) + bx.y);
    rr[2] = 0.5f * (fmaxf(ax.z + ay.z, 0.f) + cy.z * (gx.z + ga.z) + bx.z);
    rr[3] = 0.5f * (fmaxf(ax.w + ay.w, 0.f) + cy.w * (gx.w + ga.w) + bx.w);
    __builtin_nontemporal_store(rr, (f32x4*)(out + ((size_t)b * NPAIR + p) * H_DIM + o));
  }
}

extern "C" void kernel_launch(void* const* d_in, const int* in_sizes, int n_in,
                              void* d_out, int out_size, void* d_ws, size_t ws_size,
                              hipStream_t stream) {
  const float* x      = (const float*)d_in[0];  // (8,128,768)
  const float* y      = (const float*)d_in[1];  // (8,128,768)
  const float* catW   = (const float*)d_in[2];  // (768,1536)
  const float* catb   = (const float*)d_in[3];  // (768,)
  const float* beta   = (const float*)d_in[4];  // (768,)
  const float* gamma  = (const float*)d_in[5];  // (768,)
  const float* betaW  = (const float*)d_in[6];  // (768,768)
  const float* gammaW = (const float*)d_in[7];  // (768,768)

  // workspace layout (~17.3 MB total)
  char* ws = (char*)d_ws;
  unsigned short* Xb   = (unsigned short*)(ws);              // 1,572,864
  unsigned short* Yb   = (unsigned short*)(ws + 1572864);    // 1,572,864
  unsigned short* Wb   = (unsigned short*)(ws + 3145728);    // 4,718,592
  unsigned short* P    = (unsigned short*)(ws + 7864320);    // 6,291,456 (bf16 1024x3072)
  float*          Cy   = (float*)(ws + 14155776);            // 3,145,728 (fp32 1024x768)
  float*          bias = (float*)(ws + 17301504);            // 12,288
  float*          out  = (float*)d_out;                      // (8,8256,768) fp32

  prep<<<MROWS + 2304 + 3, 256, 0, stream>>>(x, y, catW, betaW, gammaW, catb, beta, Xb, Yb, Wb, Cy, bias);
  gemm_bt<<<dim3(16, 48), 256, 0, stream>>>(Xb, Yb, Wb, bias, P);
  epilogue<<<dim3(NPAIR / CHUNK, B_DIM), 192, 0, stream>>>(P, Cy, gamma, out);
}

// Round 2
// 239.835 us; speedup vs baseline: 1.0042x; 1.0042x over previous
//
#include <hip/hip_runtime.h>
#include <hip/hip_bf16.h>
#include <math.h>
#include <stdint.h>

// Problem constants (B,S,H) = (8,128,768)
#define S_LEN 128
#define H_DIM 768
#define B_DIM 8
#define NPAIR 8256          // S*(S+1)/2
#define MROWS 1024          // B*S
#define NTOT  3072          // 4*H : [Ax | Bx(+beta) | Gx | Ay(+cat_b)]
#define EPSC  1e-12f
#define CHUNK 8             // j's per epilogue block

typedef __bf16 bf16x8 __attribute__((ext_vector_type(8)));
typedef float  f32x4  __attribute__((ext_vector_type(4)));

// RNE float -> bf16 (inputs finite)
static __device__ __forceinline__ unsigned short f2bf(float f) {
  union { float f; unsigned u; } a; a.f = f;
  unsigned u = a.u;
  u += 0x7fffu + ((u >> 16) & 1u);
  return (unsigned short)(u >> 16);
}
static __device__ __forceinline__ float bf2f(unsigned short s) {
  union { unsigned u; float f; } a; a.u = ((unsigned)s) << 16;
  return a.f;
}
static __device__ __forceinline__ float4 ld_bf4(const unsigned short* p) {
  ushort4 u = *(const ushort4*)p;
  float4 f; f.x = bf2f(u.x); f.y = bf2f(u.y); f.z = bf2f(u.z); f.w = bf2f(u.w);
  return f;
}
static __device__ __forceinline__ float4 cvt_bf4(ushort4 u) {
  float4 f; f.x = bf2f(u.x); f.y = bf2f(u.y); f.z = bf2f(u.z); f.w = bf2f(u.w);
  return f;
}

// -------------------- prep (unchanged from round 1) --------------------
__global__ __launch_bounds__(256) void prep(const float* __restrict__ x,
                                            const float* __restrict__ y,
                                            const float* __restrict__ catW,
                                            const float* __restrict__ betaW,
                                            const float* __restrict__ gammaW,
                                            const float* __restrict__ catb,
                                            const float* __restrict__ beta,
                                            unsigned short* __restrict__ Xb,
                                            unsigned short* __restrict__ Yb,
                                            unsigned short* __restrict__ Wb,
                                            float* __restrict__ Cy,
                                            float* __restrict__ bias) {
  __shared__ float ls[4], ls2[4];
  const int bid = blockIdx.x;
  const int tid = threadIdx.x;
  if (bid < MROWS) {
    const int row = bid;
    const int o = tid * 4;
    float s = 0.f, s2 = 0.f;
    float4 vy = make_float4(0.f, 0.f, 0.f, 0.f);
    if (tid < 192) {
      float4 vx = *(const float4*)(x + (size_t)row * H_DIM + o);
      vy = *(const float4*)(y + (size_t)row * H_DIM + o);
      ushort4 ox; ox.x = f2bf(vx.x); ox.y = f2bf(vx.y); ox.z = f2bf(vx.z); ox.w = f2bf(vx.w);
      ushort4 oy; oy.x = f2bf(vy.x); oy.y = f2bf(vy.y); oy.z = f2bf(vy.z); oy.w = f2bf(vy.w);
      *(ushort4*)(Xb + (size_t)row * H_DIM + o) = ox;
      *(ushort4*)(Yb + (size_t)row * H_DIM + o) = oy;
      s  = vy.x + vy.y + vy.z + vy.w;
      s2 = vy.x * vy.x + vy.y * vy.y + vy.z * vy.z + vy.w * vy.w;
    }
    for (int off = 32; off > 0; off >>= 1) { s += __shfl_down(s, off); s2 += __shfl_down(s2, off); }
    if ((tid & 63) == 0) { ls[tid >> 6] = s; ls2[tid >> 6] = s2; }
    __syncthreads();
    const float S1 = ls[0] + ls[1] + ls[2] + ls[3];
    const float S2 = ls2[0] + ls2[1] + ls2[2] + ls2[3];
    const float m  = S1 / H_DIM;
    const float var = S2 / H_DIM - m * m;
    const float st = var + EPSC;                 // reference: std = (var+eps)**2
    const float iv = 1.0f / (st * st);
    if (tid < 192) {
      float4 cy;
      cy.x = (vy.x - m) * iv; cy.y = (vy.y - m) * iv;
      cy.z = (vy.z - m) * iv; cy.w = (vy.w - m) * iv;
      *(float4*)(Cy + (size_t)row * H_DIM + o) = cy;
    }
  } else if (bid < MROWS + 2304) {
    // ---- pack weights: Wb[3072][768] bf16 ----
    int idx = (bid - MROWS) * 256 + tid;     // one float4 per thread
    int e = idx * 4;
    int n = e / H_DIM, k = e % H_DIM;
    const float* src;
    if      (n < 768)  src = catW   + (size_t)n * 1536 + k;
    else if (n < 1536) src = betaW  + (size_t)(n - 768) * 768 + k;
    else if (n < 2304) src = gammaW + (size_t)(n - 1536) * 768 + k;
    else               src = catW   + (size_t)(n - 2304) * 1536 + 768 + k;
    float4 v = *(const float4*)src;
    ushort4 o4; o4.x = f2bf(v.x); o4.y = f2bf(v.y); o4.z = f2bf(v.z); o4.w = f2bf(v.w);
    *(ushort4*)(Wb + e) = o4;
  } else {
    // ---- pack bias3072: [0 | beta | 0(gamma kept separate) | cat_b] ----
    int idx = (bid - MROWS - 2304) * 256 + tid;
    int e = idx * 4;
    float4 v = make_float4(0.f, 0.f, 0.f, 0.f);
    if (e >= 768 && e < 1536) v = *(const float4*)(beta + (e - 768));
    else if (e >= 2304)       v = *(const float4*)(catb + (e - 2304));
    *(float4*)(bias + e) = v;
  }
}

// -------------------- MFMA GEMM (unchanged from round 1) --------------------
__device__ __forceinline__ void gload_lds16(const void* g, void* l) {
  __builtin_amdgcn_global_load_lds(
      (const __attribute__((address_space(1))) unsigned int*)(uintptr_t)g,
      (__attribute__((address_space(3))) unsigned int*)(uintptr_t)l,
      16, 0, 0);
}

__global__ __launch_bounds__(256) void gemm_bt(const unsigned short* __restrict__ Xb,
                                               const unsigned short* __restrict__ Yb,
                                               const unsigned short* __restrict__ Wb,
                                               const float* __restrict__ bias,
                                               unsigned short* __restrict__ P) {
  __shared__ unsigned short As[2][64 * 64];
  __shared__ unsigned short Bs[2][64 * 64];
  const int m0 = blockIdx.x * 64;
  const int n0 = blockIdx.y * 64;
  const unsigned short* A = (n0 < 2304) ? Xb : Yb;
  const unsigned short* Arow = A + (size_t)m0 * H_DIM;
  const unsigned short* Brow = Wb + (size_t)n0 * H_DIM;

  const int tid  = threadIdx.x;
  const int lane = tid & 63;
  const int wave = tid >> 6;
  const int wm = (wave >> 1) * 32;
  const int wn = (wave & 1) * 32;
  const int quad = lane >> 4;
  const int r    = lane & 15;

  const int q0 = tid, q1 = tid + 256;
  const int sr0 = q0 >> 3, sc0 = (q0 & 7) ^ (sr0 & 7);
  const int sr1 = q1 >> 3, sc1 = (q1 & 7) ^ (sr1 & 7);
  const size_t aoff0 = (size_t)sr0 * H_DIM + sc0 * 8;
  const size_t aoff1 = (size_t)sr1 * H_DIM + sc1 * 8;

  int ard[2][2], brd[2][2];
#pragma unroll
  for (int ks = 0; ks < 2; ++ks)
#pragma unroll
    for (int mi = 0; mi < 2; ++mi) {
      const int rowA = wm + mi * 16 + r;
      const int rowB = wn + mi * 16 + r;
      ard[ks][mi] = rowA * 64 + ((((ks << 2) | quad) ^ (rowA & 7)) << 3);
      brd[ks][mi] = rowB * 64 + ((((ks << 2) | quad) ^ (rowB & 7)) << 3);
    }

  f32x4 acc[2][2] = {};

  auto stage = [&](int buf, int k0) {
    gload_lds16(Arow + aoff0 + k0, &As[buf][q0 * 8]);
    gload_lds16(Arow + aoff1 + k0, &As[buf][q1 * 8]);
    gload_lds16(Brow + aoff0 + k0, &Bs[buf][q0 * 8]);
    gload_lds16(Brow + aoff1 + k0, &Bs[buf][q1 * 8]);
  };
  auto compute = [&](int buf) {
    bf16x8 af[2][2], bfr[2][2];
#pragma unroll
    for (int ks = 0; ks < 2; ++ks)
#pragma unroll
      for (int mi = 0; mi < 2; ++mi) {
        af[ks][mi]  = *(const bf16x8*)&As[buf][ard[ks][mi]];
        bfr[ks][mi] = *(const bf16x8*)&Bs[buf][brd[ks][mi]];
      }
#pragma unroll
    for (int ks = 0; ks < 2; ++ks)
#pragma unroll
      for (int mi = 0; mi < 2; ++mi)
#pragma unroll
        for (int ni = 0; ni < 2; ++ni)
          acc[mi][ni] = __builtin_amdgcn_mfma_f32_16x16x32_bf16(af[ks][mi], bfr[ks][ni], acc[mi][ni], 0, 0, 0);
  };

  stage(0, 0);
  __syncthreads();
  int cur = 0;
  for (int k0 = 64; k0 < H_DIM; k0 += 64) {
    stage(cur ^ 1, k0);
    compute(cur);
    __syncthreads();
    cur ^= 1;
  }
  compute(cur);

#pragma unroll
  for (int ni = 0; ni < 2; ++ni) {
    const int col = n0 + wn + ni * 16 + r;
    const float bv = bias[col];
#pragma unroll
    for (int mi = 0; mi < 2; ++mi) {
      const int row = m0 + wm + mi * 16 + quad * 4;
#pragma unroll
      for (int reg = 0; reg < 4; ++reg)
        P[(size_t)(row + reg) * NTOT + col] = f2bf(acc[mi][ni][reg] + bv);
    }
  }
}

// -------------------- epilogue v2: one (b, i, j-chunk) per block, straight-line --------------------
// out = 0.5*(relu(ax+ay) + cy*(gx+gamma) + bx)   [cat_b folded into ay, beta into bx]
// Grid (i, jc, b): i-row loaded ONCE per block; the 8 j-iterations have unconditional,
// independent loads (j=jc*8+t is always a valid row) gathered up-front into statically
// indexed register arrays -> full latency overlap within a block. Store predicate j>=i
// is BLOCK-uniform (scalar branch, no divergence). Numerics bitwise-identical to round 1.
__global__ __launch_bounds__(192) void epilogue(const unsigned short* __restrict__ P,
                                                const float* __restrict__ Cy,
                                                const float* __restrict__ gamma,
                                                float* __restrict__ out) {
  const int i  = blockIdx.x;
  const int j0 = blockIdx.y * CHUNK;
  const int b  = blockIdx.z;
  if (j0 + CHUNK - 1 < i) return;                 // block entirely left of diagonal

  const int o = threadIdx.x * 4;
  const size_t ri = (size_t)(b * S_LEN + i) * NTOT;

  // gather phase: all loads independent, issued back-to-back
  ushort4 axu = *(const ushort4*)(P + ri + o);
  ushort4 bxu = *(const ushort4*)(P + ri + 768 + o);
  ushort4 gxu = *(const ushort4*)(P + ri + 1536 + o);
  float4  ga  = *(const float4*)(gamma + o);

  ushort4 ayu[CHUNK];
  float4  cyv[CHUNK];
#pragma unroll
  for (int t = 0; t < CHUNK; ++t) {
    const int rowj = b * S_LEN + j0 + t;
    ayu[t] = *(const ushort4*)(P + (size_t)rowj * NTOT + 2304 + o);
    cyv[t] = *(const float4*)(Cy + (size_t)rowj * H_DIM + o);
  }

  const float4 ax = cvt_bf4(axu);
  const float4 bx = cvt_bf4(bxu);
  const float4 gx = cvt_bf4(gxu);
  const float g0 = gx.x + ga.x, g1 = gx.y + ga.y, g2 = gx.z + ga.z, g3 = gx.w + ga.w;

  const int off_i = i * (257 - i) / 2 - i;        // p = off_i + j
  float* obase = out + ((size_t)b * NPAIR + off_i) * H_DIM + o;

#pragma unroll
  for (int t = 0; t < CHUNK; ++t) {
    const int j = j0 + t;
    if (j < i) continue;                          // block-uniform scalar predicate
    const float4 ay = cvt_bf4(ayu[t]);
    const float4 cy = cyv[t];
    f32x4 rr;
    rr[0] = 0.5f * (fmaxf(ax.x + ay.x, 0.f) + cy.x * g0 + bx.x);
    rr[1] = 0.5f * (fmaxf(ax.y + ay.y, 0.f) + cy.y * g1 + bx.y);
    rr[2] = 0.5f * (fmaxf(ax.z + ay.z, 0.f) + cy.z * g2 + bx.z);
    rr[3] = 0.5f * (fmaxf(ax.w + ay.w, 0.f) + cy.w * g3 + bx.w);
    __builtin_nontemporal_store(rr, (f32x4*)(obase + (size_t)j * H_DIM));
  }
}

extern "C" void kernel_launch(void* const* d_in, const int* in_sizes, int n_in,
                              void* d_out, int out_size, void* d_ws, size_t ws_size,
                              hipStream_t stream) {
  const float* x      = (const float*)d_in[0];  // (8,128,768)
  const float* y      = (const float*)d_in[1];  // (8,128,768)
  const float* catW   = (const float*)d_in[2];  // (768,1536)
  const float* catb   = (const float*)d_in[3];  // (768,)
  const float* beta   = (const float*)d_in[4];  // (768,)
  const float* gamma  = (const float*)d_in[5];  // (768,)
  const float* betaW  = (const float*)d_in[6];  // (768,768)
  const float* gammaW = (const float*)d_in[7];  // (768,768)

  // workspace layout (~17.3 MB total)
  char* ws = (char*)d_ws;
  unsigned short* Xb   = (unsigned short*)(ws);              // 1,572,864
  unsigned short* Yb   = (unsigned short*)(ws + 1572864);    // 1,572,864
  unsigned short* Wb   = (unsigned short*)(ws + 3145728);    // 4,718,592
  unsigned short* P    = (unsigned short*)(ws + 7864320);    // 6,291,456 (bf16 1024x3072)
  float*          Cy   = (float*)(ws + 14155776);            // 3,145,728 (fp32 1024x768)
  float*          bias = (float*)(ws + 17301504);            // 12,288
  float*          out  = (float*)d_out;                      // (8,8256,768) fp32

  prep<<<MROWS + 2304 + 3, 256, 0, stream>>>(x, y, catW, betaW, gammaW, catb, beta, Xb, Yb, Wb, Cy, bias);
  gemm_bt<<<dim3(16, 48), 256, 0, stream>>>(Xb, Yb, Wb, bias, P);
  epilogue<<<dim3(S_LEN, S_LEN / CHUNK, B_DIM), 192, 0, stream>>>(P, Cy, gamma, out);
}